// Round 1
// baseline (3210.793 us; speedup 1.0000x reference)
//
#include <hip/hip_runtime.h>
#include <hip/hip_bf16.h>

#define B_ 4
#define S_ 2048
#define E_ 1024
#define H_ 16
#define D_ 64

// ---------------------------------------------------------------------------
// Sparse mask, closed form (fairseq SparseMultiheadAttention, stride=128, expr=32,
// causal). Verified against the Python generator:
//   local: row i attends [ (i/128)*128 .. i ]; rows i%128==0 (i>0) attend the
//          full previous block [i-128 .. i].
//   summary: cols j>=96 with j%128 in [96,127], or j%128==0 && j>=128.
__device__ __forceinline__ bool sp_allowed(int i, int j) {
  if (j > i) return false;
  bool local;
  if ((i & 127) == 0 && i != 0) local = (j >= i - 128);
  else                          local = (j >= ((i >> 7) << 7));
  int jm = j & 127;
  bool summ = (j >= 96) && ((jm >= 96) || (jm == 0 && j >= 128));
  return local || summ;
}

// ---------------------------------------------------------------------------
// LayerNorm over E_=1024, one block (256 thr) per row, float4 loads.
__global__ __launch_bounds__(256) void ln_kernel(const float* __restrict__ x,
                                                 const float* __restrict__ g,
                                                 const float* __restrict__ b,
                                                 float* __restrict__ o) {
  int row = blockIdx.x;
  int t = threadIdx.x;
  const float* xr = x + (size_t)row * E_;
  float4 v = *(const float4*)(xr + t * 4);
  float s  = v.x + v.y + v.z + v.w;
  float ss = v.x * v.x + v.y * v.y + v.z * v.z + v.w * v.w;
#pragma unroll
  for (int off = 1; off < 64; off <<= 1) {
    s  += __shfl_xor(s, off);
    ss += __shfl_xor(ss, off);
  }
  __shared__ float sh[8];
  if ((t & 63) == 0) { sh[t >> 6] = s; sh[4 + (t >> 6)] = ss; }
  __syncthreads();
  s  = sh[0] + sh[1] + sh[2] + sh[3];
  ss = sh[4] + sh[5] + sh[6] + sh[7];
  float mu  = s * (1.0f / E_);
  float var = ss * (1.0f / E_) - mu * mu;
  float rstd = rsqrtf(var + 1e-5f);
  float4 gg = *(const float4*)(g + t * 4);
  float4 bb = *(const float4*)(b + t * 4);
  float4 out;
  out.x = (v.x - mu) * rstd * gg.x + bb.x;
  out.y = (v.y - mu) * rstd * gg.y + bb.y;
  out.z = (v.z - mu) * rstd * gg.z + bb.z;
  out.w = (v.w - mu) * rstd * gg.w + bb.w;
  *(float4*)(o + (size_t)row * E_ + t * 4) = out;
}

// ---------------------------------------------------------------------------
// fp32 GEMM: C[M,N] = epilogue( A[M,K] @ Bw[N,K]^T ).
// epilogue: v = (acc + bias[n]) * scale; if(act) v = gelu_tanh(v); if(res) v += res[m,n].
// 128x128 tile, BK=16, 256 threads, 8x8 microtile (split 4+4 to keep LDS reads 2-way).
__global__ __launch_bounds__(256) void gemm_bt(const float* __restrict__ A,
                                               const float* __restrict__ Bw,
                                               const float* __restrict__ bias,
                                               const float* __restrict__ res,
                                               float* __restrict__ C,
                                               int M, int N, int K,
                                               float scale, int act) {
  __shared__ float As[16][132];  // [k][m], padded: staging stores 2-way, reads broadcast
  __shared__ float Bs[16][132];  // [k][n]
  const int t = threadIdx.x;
  const int row0 = blockIdx.y * 128;
  const int col0 = blockIdx.x * 128;
  const int tr = t >> 4;        // 0..15
  const int tc = t & 15;        // 0..15
  const int lr  = t >> 2;       // 0..63 staging row
  const int lc4 = (t & 3) * 4;  // staging col (float4)

  float acc[8][8];
#pragma unroll
  for (int ii = 0; ii < 8; ++ii)
#pragma unroll
    for (int jj = 0; jj < 8; ++jj) acc[ii][jj] = 0.f;

  for (int k0 = 0; k0 < K; k0 += 16) {
    float4 a0 = *(const float4*)(A + (size_t)(row0 + lr)      * K + k0 + lc4);
    float4 a1 = *(const float4*)(A + (size_t)(row0 + 64 + lr) * K + k0 + lc4);
    float4 b0 = *(const float4*)(Bw + (size_t)(col0 + lr)      * K + k0 + lc4);
    float4 b1 = *(const float4*)(Bw + (size_t)(col0 + 64 + lr) * K + k0 + lc4);
    __syncthreads();  // previous iter's LDS reads done
    As[lc4 + 0][lr] = a0.x; As[lc4 + 1][lr] = a0.y; As[lc4 + 2][lr] = a0.z; As[lc4 + 3][lr] = a0.w;
    As[lc4 + 0][64 + lr] = a1.x; As[lc4 + 1][64 + lr] = a1.y; As[lc4 + 2][64 + lr] = a1.z; As[lc4 + 3][64 + lr] = a1.w;
    Bs[lc4 + 0][lr] = b0.x; Bs[lc4 + 1][lr] = b0.y; Bs[lc4 + 2][lr] = b0.z; Bs[lc4 + 3][lr] = b0.w;
    Bs[lc4 + 0][64 + lr] = b1.x; Bs[lc4 + 1][64 + lr] = b1.y; Bs[lc4 + 2][64 + lr] = b1.z; Bs[lc4 + 3][64 + lr] = b1.w;
    __syncthreads();
#pragma unroll
    for (int kk = 0; kk < 16; ++kk) {
      float av[8], bv[8];
      *(float4*)(av)     = *(const float4*)&As[kk][tr * 4];
      *(float4*)(av + 4) = *(const float4*)&As[kk][64 + tr * 4];
      *(float4*)(bv)     = *(const float4*)&Bs[kk][tc * 4];
      *(float4*)(bv + 4) = *(const float4*)&Bs[kk][64 + tc * 4];
#pragma unroll
      for (int ii = 0; ii < 8; ++ii)
#pragma unroll
        for (int jj = 0; jj < 8; ++jj) acc[ii][jj] += av[ii] * bv[jj];
    }
  }

  const float* bias_p = bias + col0;
#pragma unroll
  for (int ii = 0; ii < 8; ++ii) {
    int rloc = (ii < 4) ? (tr * 4 + ii) : (64 + tr * 4 + ii - 4);
    size_t rowoff = (size_t)(row0 + rloc) * N + col0;
#pragma unroll
    for (int hh = 0; hh < 2; ++hh) {
      int cb = hh * 64 + tc * 4;
      float4 bb4 = *(const float4*)(bias_p + cb);
      float vv[4];
#pragma unroll
      for (int jj = 0; jj < 4; ++jj) {
        float u = (acc[ii][hh * 4 + jj] + ((&bb4.x)[jj])) * scale;
        if (act) {
          float u3 = u * u * u;
          u = 0.5f * u * (1.0f + tanhf(0.7978845608028654f * (u + 0.044715f * u3)));
        }
        vv[jj] = u;
      }
      if (res) {
        float4 rr4 = *(const float4*)(res + rowoff + cb);
        vv[0] += rr4.x; vv[1] += rr4.y; vv[2] += rr4.z; vv[3] += rr4.w;
      }
      *(float4*)(C + rowoff + cb) = make_float4(vv[0], vv[1], vv[2], vv[3]);
    }
  }
}

// ---------------------------------------------------------------------------
// Sparse flash attention. Block = (qt, h, b), 256 thr; 64 q-rows per block.
// Thread (r = t>>2, g = t&3) owns q-row r's d-slice [16g,16g+16).
// Tiles: packed far-summary columns (all allowed for every row in the tile),
// then near tiles jb in [qt-2, qt] with the closed-form mask (diagonal last,
// which flushes any all-masked-tile garbage through alpha=exp(-1e30-m)=0).
__global__ __launch_bounds__(256) void attn_kernel(const float* __restrict__ qp,
                                                   const float* __restrict__ kp,
                                                   const float* __restrict__ vp,
                                                   float* __restrict__ op) {
  const int qt = blockIdx.x;
  const int hh = blockIdx.y;
  const int bb = blockIdx.z;
  const int t = threadIdx.x;
  const int r = t >> 2;
  const int g = t & 3;
  const int i = qt * 64 + r;

  __shared__ float Ks[64][68];  // pad 68: staging 2-way, reads broadcast
  __shared__ float Vs[64][68];
  __shared__ int jflag[64];

  float qf[16];
  {
    const float* qrow = qp + ((size_t)bb * S_ + i) * E_ + hh * D_ + g * 16;
    *(float4*)(qf)      = ((const float4*)qrow)[0];
    *(float4*)(qf + 4)  = ((const float4*)qrow)[1];
    *(float4*)(qf + 8)  = ((const float4*)qrow)[2];
    *(float4*)(qf + 12) = ((const float4*)qrow)[3];
  }

  float m = -1e30f, l = 0.f;
  float oa[16];
#pragma unroll
  for (int c = 0; c < 16; ++c) oa[c] = 0.f;

  const int nnear0 = (qt >= 2) ? (qt - 2) : 0;
  const int L = (qt - 2) * 64;  // far columns must be < L (disjoint from near tiles)
  int nfar = 0;
  if (L > 96) {
    int tmax = (L - 96 + 127) >> 7;  // # summary blocks with base < L
    int P = tmax * 33;               // upper bound on packed count; per-col jg<L check below
    nfar = (P + 63) >> 6;
  }
  const int ntiles = nfar + (qt - nnear0 + 1);

  for (int tile = 0; tile < ntiles; ++tile) {
    int jg; bool valid;
    if (tile < nfar) {
      int p = tile * 64 + r;
      int tt = p / 33;
      int oo = p - tt * 33;
      jg = 96 + (tt << 7) + oo;     // summary col (monotone in p)
      valid = (jg < L);
    } else {
      int jb = nnear0 + (tile - nfar);
      jg = (jb << 6) + r;
      valid = true;
    }
    __syncthreads();  // previous tile's LDS reads done
    if (valid) {
      const float* krow = kp + ((size_t)bb * S_ + jg) * E_ + hh * D_ + g * 16;
      const float* vrow = vp + ((size_t)bb * S_ + jg) * E_ + hh * D_ + g * 16;
      float4* kd = (float4*)&Ks[r][g * 16];
      float4* vd = (float4*)&Vs[r][g * 16];
      kd[0] = ((const float4*)krow)[0]; kd[1] = ((const float4*)krow)[1];
      kd[2] = ((const float4*)krow)[2]; kd[3] = ((const float4*)krow)[3];
      vd[0] = ((const float4*)vrow)[0]; vd[1] = ((const float4*)vrow)[1];
      vd[2] = ((const float4*)vrow)[2]; vd[3] = ((const float4*)vrow)[3];
    } else {
      float4 z = make_float4(0.f, 0.f, 0.f, 0.f);
      float4* kd = (float4*)&Ks[r][g * 16];
      float4* vd = (float4*)&Vs[r][g * 16];
      kd[0] = z; kd[1] = z; kd[2] = z; kd[3] = z;
      vd[0] = z; vd[1] = z; vd[2] = z; vd[3] = z;  // Vs MUST be finite (0*NaN guard)
    }
    if (g == 0) jflag[r] = valid ? jg : -1;
    __syncthreads();

    // ---- scores: each (r,g) computes partial dots for all 64 cols, 4-lane reduce;
    // lane g keeps cols [16g,16g+16). Full unroll → sreg stays in registers.
    float sreg[16];
#pragma unroll
    for (int j2 = 0; j2 < 64; ++j2) {
      float kf[16];
      *(float4*)(kf)      = *(const float4*)&Ks[j2][g * 16];
      *(float4*)(kf + 4)  = *(const float4*)&Ks[j2][g * 16 + 4];
      *(float4*)(kf + 8)  = *(const float4*)&Ks[j2][g * 16 + 8];
      *(float4*)(kf + 12) = *(const float4*)&Ks[j2][g * 16 + 12];
      float pp = 0.f;
#pragma unroll
      for (int c = 0; c < 16; ++c) pp += qf[c] * kf[c];
      pp += __shfl_xor(pp, 1);
      pp += __shfl_xor(pp, 2);
      int jg2 = jflag[j2];
      float sv = (jg2 >= 0 && sp_allowed(i, jg2)) ? pp : -1e30f;
      if ((j2 >> 4) == g) sreg[j2 & 15] = sv;
    }

    // ---- online softmax (per row across the 4 g-lanes)
    float tmax_ = sreg[0];
#pragma unroll
    for (int c = 1; c < 16; ++c) tmax_ = fmaxf(tmax_, sreg[c]);
    tmax_ = fmaxf(tmax_, __shfl_xor(tmax_, 1));
    tmax_ = fmaxf(tmax_, __shfl_xor(tmax_, 2));
    float mnew = fmaxf(m, tmax_);
    float alpha = __expf(m - mnew);
    float pr[16]; float psum = 0.f;
#pragma unroll
    for (int c = 0; c < 16; ++c) { pr[c] = __expf(sreg[c] - mnew); psum += pr[c]; }
    psum += __shfl_xor(psum, 1);
    psum += __shfl_xor(psum, 2);
    l = l * alpha + psum;
    m = mnew;
#pragma unroll
    for (int c = 0; c < 16; ++c) oa[c] *= alpha;

    // ---- PV: broadcast each lane's 16 p-values to its 3 siblings via shfl
#pragma unroll
    for (int sg = 0; sg < 4; ++sg) {
      int lsrc = ((t & 63) & ~3) | sg;
#pragma unroll
      for (int c = 0; c < 16; ++c) {
        float pb = __shfl(pr[c], lsrc, 64);
        int j2 = (sg << 4) + c;
        float vf[16];
        *(float4*)(vf)      = *(const float4*)&Vs[j2][g * 16];
        *(float4*)(vf + 4)  = *(const float4*)&Vs[j2][g * 16 + 4];
        *(float4*)(vf + 8)  = *(const float4*)&Vs[j2][g * 16 + 8];
        *(float4*)(vf + 12) = *(const float4*)&Vs[j2][g * 16 + 12];
#pragma unroll
        for (int d2 = 0; d2 < 16; ++d2) oa[d2] += pb * vf[d2];
      }
    }
  }

  float inv = 1.0f / l;  // every row has its diagonal allowed → l > 0
#pragma unroll
  for (int c = 0; c < 16; ++c) oa[c] *= inv;
  float* orow = op + ((size_t)bb * S_ + i) * E_ + hh * D_ + g * 16;
  ((float4*)orow)[0] = *(float4*)(oa);
  ((float4*)orow)[1] = *(float4*)(oa + 4);
  ((float4*)orow)[2] = *(float4*)(oa + 8);
  ((float4*)orow)[3] = *(float4*)(oa + 12);
}

// ---------------------------------------------------------------------------
extern "C" void kernel_launch(void* const* d_in, const int* in_sizes, int n_in,
                              void* d_out, int out_size, void* d_ws, size_t ws_size,
                              hipStream_t stream) {
  const float* x      = (const float*)d_in[0];
  const float* ln1_g  = (const float*)d_in[1];
  const float* ln1_b  = (const float*)d_in[2];
  const float* ln2_g  = (const float*)d_in[3];
  const float* ln2_b  = (const float*)d_in[4];
  const float* wq     = (const float*)d_in[5];
  const float* bq     = (const float*)d_in[6];
  const float* wk     = (const float*)d_in[7];
  const float* bk     = (const float*)d_in[8];
  const float* wv     = (const float*)d_in[9];
  const float* bv     = (const float*)d_in[10];
  const float* wo     = (const float*)d_in[11];
  const float* bo     = (const float*)d_in[12];
  const float* w_fc   = (const float*)d_in[13];
  const float* b_fc   = (const float*)d_in[14];
  const float* w_proj = (const float*)d_in[15];
  const float* b_proj = (const float*)d_in[16];
  // d_in[17] = mask — unused; pattern computed in closed form in-kernel.

  float* ws = (float*)d_ws;
  const int NTOK = B_ * S_;            // 8192 rows
  const size_t SZ = (size_t)NTOK * E_; // 8388608 floats
  float* h   = ws;
  float* qb  = ws + SZ;
  float* kb  = ws + 2 * SZ;
  float* vb  = ws + 3 * SZ;
  float* ab  = ws + 4 * SZ;
  float* h2  = ws + 5 * SZ;
  float* l2o = ws + 6 * SZ;
  float* fcb = qb;  // reuse q/k/v/attn region (4*SZ floats) for the [8192,4096] FC output
  float* out = (float*)d_out;

  ln_kernel<<<NTOK, 256, 0, stream>>>(x, ln1_g, ln1_b, h);

  dim3 g1(E_ / 128, NTOK / 128);           // (8, 64)
  gemm_bt<<<g1, 256, 0, stream>>>(h, wq, bq, nullptr, qb, NTOK, E_, E_, 0.125f, 0);
  gemm_bt<<<g1, 256, 0, stream>>>(h, wk, bk, nullptr, kb, NTOK, E_, E_, 1.0f, 0);
  gemm_bt<<<g1, 256, 0, stream>>>(h, wv, bv, nullptr, vb, NTOK, E_, E_, 1.0f, 0);

  attn_kernel<<<dim3(S_ / 64, H_, B_), 256, 0, stream>>>(qb, kb, vb, ab);

  gemm_bt<<<g1, 256, 0, stream>>>(ab, wo, bo, h, h2, NTOK, E_, E_, 1.0f, 0);

  ln_kernel<<<NTOK, 256, 0, stream>>>(h2, ln2_g, ln2_b, l2o);

  dim3 g2(4 * E_ / 128, NTOK / 128);       // (32, 64)
  gemm_bt<<<g2, 256, 0, stream>>>(l2o, w_fc, b_fc, nullptr, fcb, NTOK, 4 * E_, E_, 1.0f, 1);
  gemm_bt<<<g1, 256, 0, stream>>>(fcb, w_proj, b_proj, h2, out, NTOK, E_, 4 * E_, 1.0f, 0);
}

// Round 2
// 1819.784 us; speedup vs baseline: 1.7644x; 1.7644x over previous
//
#include <hip/hip_runtime.h>
#include <hip/hip_bf16.h>

#define B_ 4
#define S_ 2048
#define E_ 1024
#define H_ 16
#define D_ 64

typedef __bf16 bf16x8 __attribute__((ext_vector_type(8)));
typedef __bf16 bf16x4 __attribute__((ext_vector_type(4)));
typedef float  f32x4  __attribute__((ext_vector_type(4)));

// global -> LDS direct copy, 16B per lane. LDS dest must be the wave-uniform
// base; HW writes lane i at base + i*16.
__device__ __forceinline__ void gl_lds16(const void* g, void* l) {
  __builtin_amdgcn_global_load_lds((const __attribute__((address_space(1))) void*)g,
                                   (__attribute__((address_space(3))) void*)l, 16, 0, 0);
}

// ---------------------------------------------------------------------------
// Sparse mask, closed form (verified vs Python generator).
__device__ __forceinline__ bool sp_allowed(int i, int j) {
  if (j > i) return false;
  bool local;
  if ((i & 127) == 0 && i != 0) local = (j >= i - 128);
  else                          local = (j >= ((i >> 7) << 7));
  int jm = j & 127;
  bool summ = (j >= 96) && ((jm >= 96) || (jm == 0 && j >= 128));
  return local || summ;
}

// ---------------------------------------------------------------------------
// LayerNorm over E_=1024; optional fp32 out and bf16 hi/lo split outputs.
__global__ __launch_bounds__(256) void ln_kernel(const float* __restrict__ x,
                                                 const float* __restrict__ g,
                                                 const float* __restrict__ b,
                                                 float* __restrict__ o,
                                                 __bf16* __restrict__ ohi,
                                                 __bf16* __restrict__ olo) {
  int row = blockIdx.x;
  int t = threadIdx.x;
  const float* xr = x + (size_t)row * E_;
  float4 v = *(const float4*)(xr + t * 4);
  float s  = v.x + v.y + v.z + v.w;
  float ss = v.x * v.x + v.y * v.y + v.z * v.z + v.w * v.w;
#pragma unroll
  for (int off = 1; off < 64; off <<= 1) {
    s  += __shfl_xor(s, off);
    ss += __shfl_xor(ss, off);
  }
  __shared__ float sh[8];
  if ((t & 63) == 0) { sh[t >> 6] = s; sh[4 + (t >> 6)] = ss; }
  __syncthreads();
  s  = sh[0] + sh[1] + sh[2] + sh[3];
  ss = sh[4] + sh[5] + sh[6] + sh[7];
  float mu  = s * (1.0f / E_);
  float var = ss * (1.0f / E_) - mu * mu;
  float rstd = rsqrtf(var + 1e-5f);
  float4 gg = *(const float4*)(g + t * 4);
  float4 bb = *(const float4*)(b + t * 4);
  float ov[4];
  ov[0] = (v.x - mu) * rstd * gg.x + bb.x;
  ov[1] = (v.y - mu) * rstd * gg.y + bb.y;
  ov[2] = (v.z - mu) * rstd * gg.z + bb.z;
  ov[3] = (v.w - mu) * rstd * gg.w + bb.w;
  size_t base = (size_t)row * E_ + t * 4;
  if (o) *(float4*)(o + base) = make_float4(ov[0], ov[1], ov[2], ov[3]);
  if (ohi) {
    bf16x4 hv, lv;
#pragma unroll
    for (int j = 0; j < 4; ++j) {
      __bf16 hh = (__bf16)ov[j];
      hv[j] = hh;
      lv[j] = (__bf16)(ov[j] - (float)hh);
    }
    *(bf16x4*)(ohi + base) = hv;
    *(bf16x4*)(olo + base) = lv;
  }
}

// ---------------------------------------------------------------------------
// fp32 -> bf16 hi/lo split, float4 grid-stride.
__global__ __launch_bounds__(256) void split_kernel(const float* __restrict__ in,
                                                    __bf16* __restrict__ hi,
                                                    __bf16* __restrict__ lo,
                                                    int n4) {
  int idx = blockIdx.x * 256 + threadIdx.x;
  int stride = gridDim.x * 256;
  for (int i = idx; i < n4; i += stride) {
    float4 v = ((const float4*)in)[i];
    bf16x4 hv, lv;
#pragma unroll
    for (int j = 0; j < 4; ++j) {
      float f = (&v.x)[j];
      __bf16 hh = (__bf16)f;
      hv[j] = hh;
      lv[j] = (__bf16)(f - (float)hh);
    }
    ((bf16x4*)hi)[i] = hv;
    ((bf16x4*)lo)[i] = lv;
  }
}

// ---------------------------------------------------------------------------
// Split-bf16 MFMA GEMM: C[M,N] = epi( (Ah+Al)[M,K] @ (Bh+Bl)[N,K]^T )
// via Ah*Bh + Ah*Bl + Al*Bh (fp32 acc). 128x128 tile, BK=32, 4 waves.
// LDS layout per array: 512 units of 16B, unit = kgroup*128 + row, so both
// global_load_lds staging (linear) and ds_read_b128 fragment reads (16
// consecutive units per quarter-wave) are conflict-free.
// epilogue: v = (acc + bias[n]) * scale; act? gelu; res? += res[m,n];
// writes Cf (fp32) and/or Chi/Clo (bf16 split), each optional.
__global__ __launch_bounds__(256) void gemm_split(
    const __bf16* __restrict__ Ah, const __bf16* __restrict__ Al,
    const __bf16* __restrict__ Bh, const __bf16* __restrict__ Bl,
    const float* __restrict__ bias, const float* __restrict__ res,
    float* __restrict__ Cf, __bf16* __restrict__ Chi, __bf16* __restrict__ Clo,
    int M, int N, int K, float scale, int act) {
  __shared__ bf16x8 lds[2048];  // 32 KiB: Ah[0) Al[512) Bh[1024) Bl[1536)
  const int t = threadIdx.x;
  const int row0 = blockIdx.y * 128, col0 = blockIdx.x * 128;
  const int l = t & 63;
  const int w = t >> 6;
  const int wr = w >> 1, wc = w & 1;   // wave quadrant (64x64)
  const int fr = l & 15, kg = l >> 4;
  const int wbase = t & 192;           // wave-uniform staging base (units)

  f32x4 acc[4][4];
#pragma unroll
  for (int i = 0; i < 4; ++i)
#pragma unroll
    for (int j = 0; j < 4; ++j) acc[i][j] = (f32x4){0.f, 0.f, 0.f, 0.f};

  for (int k0 = 0; k0 < K; k0 += 32) {
#pragma unroll
    for (int rnd = 0; rnd < 2; ++rnd) {
      int u = rnd * 256 + t;
      int rrow = u & 127, ukg = u >> 7;
      size_t goffA = (size_t)(row0 + rrow) * K + k0 + ukg * 8;
      size_t goffB = (size_t)(col0 + rrow) * K + k0 + ukg * 8;
      int lb = rnd * 256 + wbase;
      gl_lds16(Ah + goffA, &lds[lb]);
      gl_lds16(Al + goffA, &lds[512 + lb]);
      gl_lds16(Bh + goffB, &lds[1024 + lb]);
      gl_lds16(Bl + goffB, &lds[1536 + lb]);
    }
    __syncthreads();  // drains vmcnt -> staged data visible

    bf16x8 a_h[4], a_l[4], b_h[4], b_l[4];
#pragma unroll
    for (int i = 0; i < 4; ++i) {
      a_h[i] = lds[        kg * 128 + wr * 64 + i * 16 + fr];
      a_l[i] = lds[ 512  + kg * 128 + wr * 64 + i * 16 + fr];
      b_h[i] = lds[ 1024 + kg * 128 + wc * 64 + i * 16 + fr];
      b_l[i] = lds[ 1536 + kg * 128 + wc * 64 + i * 16 + fr];
    }
#pragma unroll
    for (int i = 0; i < 4; ++i)
#pragma unroll
      for (int j = 0; j < 4; ++j)
        acc[i][j] = __builtin_amdgcn_mfma_f32_16x16x32_bf16(a_h[i], b_h[j], acc[i][j], 0, 0, 0);
#pragma unroll
    for (int i = 0; i < 4; ++i)
#pragma unroll
      for (int j = 0; j < 4; ++j)
        acc[i][j] = __builtin_amdgcn_mfma_f32_16x16x32_bf16(a_h[i], b_l[j], acc[i][j], 0, 0, 0);
#pragma unroll
    for (int i = 0; i < 4; ++i)
#pragma unroll
      for (int j = 0; j < 4; ++j)
        acc[i][j] = __builtin_amdgcn_mfma_f32_16x16x32_bf16(a_l[i], b_h[j], acc[i][j], 0, 0, 0);
    __syncthreads();  // all reads done before next overwrite
  }

  // Epilogue. C/D frag: col = lane&15, row = (lane>>4)*4 + r (guide-verified).
#pragma unroll
  for (int mi = 0; mi < 4; ++mi)
#pragma unroll
    for (int ni = 0; ni < 4; ++ni) {
      int col = col0 + wc * 64 + ni * 16 + fr;
      int rbase = row0 + wr * 64 + mi * 16 + kg * 4;
      float bsum = bias[col];
#pragma unroll
      for (int r = 0; r < 4; ++r) {
        float v = (acc[mi][ni][r] + bsum) * scale;
        if (act) {
          float zn = 0.7978845608028654f * (v + 0.044715f * v * v * v);
          float e = __expf(fminf(2.f * zn, 80.f));
          v = v * e / (e + 1.f);  // 0.5v(1+tanh(zn))
        }
        size_t off = (size_t)(rbase + r) * N + col;
        if (res) v += res[off];
        if (Cf) Cf[off] = v;
        if (Chi) {
          __bf16 hh = (__bf16)v;
          Chi[off] = hh;
          Clo[off] = (__bf16)(v - (float)hh);
        }
      }
    }
}

// ---------------------------------------------------------------------------
// Sparse flash attention (unchanged from round 1).
__global__ __launch_bounds__(256) void attn_kernel(const float* __restrict__ qp,
                                                   const float* __restrict__ kp,
                                                   const float* __restrict__ vp,
                                                   float* __restrict__ op) {
  const int qt = blockIdx.x;
  const int hh = blockIdx.y;
  const int bb = blockIdx.z;
  const int t = threadIdx.x;
  const int r = t >> 2;
  const int g = t & 3;
  const int i = qt * 64 + r;

  __shared__ float Ks[64][68];
  __shared__ float Vs[64][68];
  __shared__ int jflag[64];

  float qf[16];
  {
    const float* qrow = qp + ((size_t)bb * S_ + i) * E_ + hh * D_ + g * 16;
    *(float4*)(qf)      = ((const float4*)qrow)[0];
    *(float4*)(qf + 4)  = ((const float4*)qrow)[1];
    *(float4*)(qf + 8)  = ((const float4*)qrow)[2];
    *(float4*)(qf + 12) = ((const float4*)qrow)[3];
  }

  float m = -1e30f, l = 0.f;
  float oa[16];
#pragma unroll
  for (int c = 0; c < 16; ++c) oa[c] = 0.f;

  const int nnear0 = (qt >= 2) ? (qt - 2) : 0;
  const int L = (qt - 2) * 64;
  int nfar = 0;
  if (L > 96) {
    int tmax = (L - 96 + 127) >> 7;
    int P = tmax * 33;
    nfar = (P + 63) >> 6;
  }
  const int ntiles = nfar + (qt - nnear0 + 1);

  for (int tile = 0; tile < ntiles; ++tile) {
    int jg; bool valid;
    if (tile < nfar) {
      int p = tile * 64 + r;
      int tt = p / 33;
      int oo = p - tt * 33;
      jg = 96 + (tt << 7) + oo;
      valid = (jg < L);
    } else {
      int jb = nnear0 + (tile - nfar);
      jg = (jb << 6) + r;
      valid = true;
    }
    __syncthreads();
    if (valid) {
      const float* krow = kp + ((size_t)bb * S_ + jg) * E_ + hh * D_ + g * 16;
      const float* vrow = vp + ((size_t)bb * S_ + jg) * E_ + hh * D_ + g * 16;
      float4* kd = (float4*)&Ks[r][g * 16];
      float4* vd = (float4*)&Vs[r][g * 16];
      kd[0] = ((const float4*)krow)[0]; kd[1] = ((const float4*)krow)[1];
      kd[2] = ((const float4*)krow)[2]; kd[3] = ((const float4*)krow)[3];
      vd[0] = ((const float4*)vrow)[0]; vd[1] = ((const float4*)vrow)[1];
      vd[2] = ((const float4*)vrow)[2]; vd[3] = ((const float4*)vrow)[3];
    } else {
      float4 z = make_float4(0.f, 0.f, 0.f, 0.f);
      float4* kd = (float4*)&Ks[r][g * 16];
      float4* vd = (float4*)&Vs[r][g * 16];
      kd[0] = z; kd[1] = z; kd[2] = z; kd[3] = z;
      vd[0] = z; vd[1] = z; vd[2] = z; vd[3] = z;
    }
    if (g == 0) jflag[r] = valid ? jg : -1;
    __syncthreads();

    float sreg[16];
#pragma unroll
    for (int j2 = 0; j2 < 64; ++j2) {
      float kf[16];
      *(float4*)(kf)      = *(const float4*)&Ks[j2][g * 16];
      *(float4*)(kf + 4)  = *(const float4*)&Ks[j2][g * 16 + 4];
      *(float4*)(kf + 8)  = *(const float4*)&Ks[j2][g * 16 + 8];
      *(float4*)(kf + 12) = *(const float4*)&Ks[j2][g * 16 + 12];
      float pp = 0.f;
#pragma unroll
      for (int c = 0; c < 16; ++c) pp += qf[c] * kf[c];
      pp += __shfl_xor(pp, 1);
      pp += __shfl_xor(pp, 2);
      int jg2 = jflag[j2];
      float sv = (jg2 >= 0 && sp_allowed(i, jg2)) ? pp : -1e30f;
      if ((j2 >> 4) == g) sreg[j2 & 15] = sv;
    }

    float tmax_ = sreg[0];
#pragma unroll
    for (int c = 1; c < 16; ++c) tmax_ = fmaxf(tmax_, sreg[c]);
    tmax_ = fmaxf(tmax_, __shfl_xor(tmax_, 1));
    tmax_ = fmaxf(tmax_, __shfl_xor(tmax_, 2));
    float mnew = fmaxf(m, tmax_);
    float alpha = __expf(m - mnew);
    float pr[16]; float psum = 0.f;
#pragma unroll
    for (int c = 0; c < 16; ++c) { pr[c] = __expf(sreg[c] - mnew); psum += pr[c]; }
    psum += __shfl_xor(psum, 1);
    psum += __shfl_xor(psum, 2);
    l = l * alpha + psum;
    m = mnew;
#pragma unroll
    for (int c = 0; c < 16; ++c) oa[c] *= alpha;

#pragma unroll
    for (int sg = 0; sg < 4; ++sg) {
      int lsrc = ((t & 63) & ~3) | sg;
#pragma unroll
      for (int c = 0; c < 16; ++c) {
        float pb = __shfl(pr[c], lsrc, 64);
        int j2 = (sg << 4) + c;
        float vf[16];
        *(float4*)(vf)      = *(const float4*)&Vs[j2][g * 16];
        *(float4*)(vf + 4)  = *(const float4*)&Vs[j2][g * 16 + 4];
        *(float4*)(vf + 8)  = *(const float4*)&Vs[j2][g * 16 + 8];
        *(float4*)(vf + 12) = *(const float4*)&Vs[j2][g * 16 + 12];
#pragma unroll
        for (int d2 = 0; d2 < 16; ++d2) oa[d2] += pb * vf[d2];
      }
    }
  }

  float inv = 1.0f / l;
#pragma unroll
  for (int c = 0; c < 16; ++c) oa[c] *= inv;
  float* orow = op + ((size_t)bb * S_ + i) * E_ + hh * D_ + g * 16;
  ((float4*)orow)[0] = *(float4*)(oa);
  ((float4*)orow)[1] = *(float4*)(oa + 4);
  ((float4*)orow)[2] = *(float4*)(oa + 8);
  ((float4*)orow)[3] = *(float4*)(oa + 12);
}

// ---------------------------------------------------------------------------
extern "C" void kernel_launch(void* const* d_in, const int* in_sizes, int n_in,
                              void* d_out, int out_size, void* d_ws, size_t ws_size,
                              hipStream_t stream) {
  const float* x      = (const float*)d_in[0];
  const float* ln1_g  = (const float*)d_in[1];
  const float* ln1_b  = (const float*)d_in[2];
  const float* ln2_g  = (const float*)d_in[3];
  const float* ln2_b  = (const float*)d_in[4];
  const float* wq     = (const float*)d_in[5];
  const float* bq     = (const float*)d_in[6];
  const float* wk     = (const float*)d_in[7];
  const float* bk     = (const float*)d_in[8];
  const float* wv     = (const float*)d_in[9];
  const float* bv     = (const float*)d_in[10];
  const float* wo     = (const float*)d_in[11];
  const float* bo     = (const float*)d_in[12];
  const float* w_fc   = (const float*)d_in[13];
  const float* b_fc   = (const float*)d_in[14];
  const float* w_proj = (const float*)d_in[15];
  const float* b_proj = (const float*)d_in[16];
  // d_in[17] = mask — computed in closed form in-kernel.

  char* W = (char*)d_ws;
  const size_t MB = (size_t)1 << 20;
  const int NTOK = B_ * S_;  // 8192

  // Workspace plan (MiB offsets; total 224 = round-1 proven footprint):
  // [0,32)   h fp32                  -> l2o_hi [0,16) + l2o_lo [16,32) after WO
  // [32,64)  h_hi/h_lo               -> ab_hi/ab_lo after QKV -> wfc/wpj scratch after WO
  // [64,96)  qb                      -> h2 after attn
  // [96,160) kb,vb                   -> fcb_hi after attn
  // [160,224) ab + wqkv scratch      -> fcb_lo after split_ab (+wo scratch)
  float*  h      = (float*)(W + 0 * MB);
  __bf16* h_hi   = (__bf16*)(W + 32 * MB);
  __bf16* h_lo   = (__bf16*)(W + 48 * MB);
  float*  qb     = (float*)(W + 64 * MB);
  float*  kb     = (float*)(W + 96 * MB);
  float*  vb     = (float*)(W + 128 * MB);
  float*  ab     = (float*)(W + 160 * MB);
  __bf16* ab_hi  = h_hi;
  __bf16* ab_lo  = h_lo;
  float*  h2     = qb;
  __bf16* l2o_hi = (__bf16*)(W + 0 * MB);
  __bf16* l2o_lo = (__bf16*)(W + 16 * MB);
  __bf16* fcb_hi = (__bf16*)(W + 96 * MB);   // 64 MiB
  __bf16* fcb_lo = (__bf16*)(W + 160 * MB);  // 64 MiB
  __bf16* wq_hi  = (__bf16*)(W + 160 * MB);  // QKV-phase scratch (ab not yet live)
  __bf16* wq_lo  = (__bf16*)(W + 162 * MB);
  __bf16* wk_hi  = (__bf16*)(W + 164 * MB);
  __bf16* wk_lo  = (__bf16*)(W + 166 * MB);
  __bf16* wv_hi  = (__bf16*)(W + 168 * MB);
  __bf16* wv_lo  = (__bf16*)(W + 170 * MB);
  __bf16* wo_hi  = (__bf16*)(W + 160 * MB);  // after split_ab (ab fp32 dead)
  __bf16* wo_lo  = (__bf16*)(W + 162 * MB);
  __bf16* wfc_hi = (__bf16*)(W + 32 * MB);   // after WO (ab_hi/lo dead)
  __bf16* wfc_lo = (__bf16*)(W + 40 * MB);
  __bf16* wpj_hi = (__bf16*)(W + 32 * MB);
  __bf16* wpj_lo = (__bf16*)(W + 40 * MB);
  float* out = (float*)d_out;

  const int SPLIT_BLKS = 2048;
  const int nw1 = E_ * E_ / 4;          // 1M-elem weights, float4 count
  const int nw4 = 4 * E_ * E_ / 4;      // 4M-elem weights
  const int nab = NTOK * E_ / 4;

  // LN1 -> h fp32 + bf16 split
  ln_kernel<<<NTOK, 256, 0, stream>>>(x, ln1_g, ln1_b, h, h_hi, h_lo);

  // QKV
  split_kernel<<<SPLIT_BLKS, 256, 0, stream>>>(wq, wq_hi, wq_lo, nw1);
  split_kernel<<<SPLIT_BLKS, 256, 0, stream>>>(wk, wk_hi, wk_lo, nw1);
  split_kernel<<<SPLIT_BLKS, 256, 0, stream>>>(wv, wv_hi, wv_lo, nw1);
  dim3 g1(E_ / 128, NTOK / 128);  // (8, 64)
  gemm_split<<<g1, 256, 0, stream>>>(h_hi, h_lo, wq_hi, wq_lo, bq, nullptr,
                                     qb, nullptr, nullptr, NTOK, E_, E_, 0.125f, 0);
  gemm_split<<<g1, 256, 0, stream>>>(h_hi, h_lo, wk_hi, wk_lo, bk, nullptr,
                                     kb, nullptr, nullptr, NTOK, E_, E_, 1.0f, 0);
  gemm_split<<<g1, 256, 0, stream>>>(h_hi, h_lo, wv_hi, wv_lo, bv, nullptr,
                                     vb, nullptr, nullptr, NTOK, E_, E_, 1.0f, 0);

  // Sparse attention
  attn_kernel<<<dim3(S_ / 64, H_, B_), 256, 0, stream>>>(qb, kb, vb, ab);

  // WO projection + residual(h) -> h2
  split_kernel<<<SPLIT_BLKS, 256, 0, stream>>>(ab, ab_hi, ab_lo, nab);
  split_kernel<<<SPLIT_BLKS, 256, 0, stream>>>(wo, wo_hi, wo_lo, nw1);
  gemm_split<<<g1, 256, 0, stream>>>(ab_hi, ab_lo, wo_hi, wo_lo, bo, h,
                                     h2, nullptr, nullptr, NTOK, E_, E_, 1.0f, 0);

  // LN2 -> bf16 split only
  ln_kernel<<<NTOK, 256, 0, stream>>>(h2, ln2_g, ln2_b, nullptr, l2o_hi, l2o_lo);

  // FC + GELU -> bf16 split only
  split_kernel<<<SPLIT_BLKS, 256, 0, stream>>>(w_fc, wfc_hi, wfc_lo, nw4);
  dim3 g2(4 * E_ / 128, NTOK / 128);  // (32, 64)
  gemm_split<<<g2, 256, 0, stream>>>(l2o_hi, l2o_lo, wfc_hi, wfc_lo, b_fc, nullptr,
                                     nullptr, fcb_hi, fcb_lo, NTOK, 4 * E_, E_, 1.0f, 1);

  // PROJ + residual(h2) -> out
  split_kernel<<<SPLIT_BLKS, 256, 0, stream>>>(w_proj, wpj_hi, wpj_lo, nw4);
  gemm_split<<<g1, 256, 0, stream>>>(fcb_hi, fcb_lo, wpj_hi, wpj_lo, b_proj, h2,
                                     out, nullptr, nullptr, NTOK, E_, 4 * E_, 1.0f, 0);
}

// Round 3
// 1429.239 us; speedup vs baseline: 2.2465x; 1.2733x over previous
//
#include <hip/hip_runtime.h>
#include <hip/hip_bf16.h>

#define B_ 4
#define S_ 2048
#define E_ 1024
#define H_ 16
#define D_ 64

typedef __bf16 bf16x8 __attribute__((ext_vector_type(8)));
typedef __bf16 bf16x4 __attribute__((ext_vector_type(4)));
typedef float  f32x4  __attribute__((ext_vector_type(4)));

__device__ __forceinline__ void gl_lds16(const void* g, void* l) {
  __builtin_amdgcn_global_load_lds((const __attribute__((address_space(1))) void*)g,
                                   (__attribute__((address_space(3))) void*)l, 16, 0, 0);
}

// ---------------------------------------------------------------------------
// LayerNorm over E_=1024; optional fp32 out and bf16 hi/lo split outputs.
__global__ __launch_bounds__(256) void ln_kernel(const float* __restrict__ x,
                                                 const float* __restrict__ g,
                                                 const float* __restrict__ b,
                                                 float* __restrict__ o,
                                                 __bf16* __restrict__ ohi,
                                                 __bf16* __restrict__ olo) {
  int row = blockIdx.x;
  int t = threadIdx.x;
  const float* xr = x + (size_t)row * E_;
  float4 v = *(const float4*)(xr + t * 4);
  float s  = v.x + v.y + v.z + v.w;
  float ss = v.x * v.x + v.y * v.y + v.z * v.z + v.w * v.w;
#pragma unroll
  for (int off = 1; off < 64; off <<= 1) {
    s  += __shfl_xor(s, off);
    ss += __shfl_xor(ss, off);
  }
  __shared__ float sh[8];
  if ((t & 63) == 0) { sh[t >> 6] = s; sh[4 + (t >> 6)] = ss; }
  __syncthreads();
  s  = sh[0] + sh[1] + sh[2] + sh[3];
  ss = sh[4] + sh[5] + sh[6] + sh[7];
  float mu  = s * (1.0f / E_);
  float var = ss * (1.0f / E_) - mu * mu;
  float rstd = rsqrtf(var + 1e-5f);
  float4 gg = *(const float4*)(g + t * 4);
  float4 bb = *(const float4*)(b + t * 4);
  float ov[4];
  ov[0] = (v.x - mu) * rstd * gg.x + bb.x;
  ov[1] = (v.y - mu) * rstd * gg.y + bb.y;
  ov[2] = (v.z - mu) * rstd * gg.z + bb.z;
  ov[3] = (v.w - mu) * rstd * gg.w + bb.w;
  size_t base = (size_t)row * E_ + t * 4;
  if (o) *(float4*)(o + base) = make_float4(ov[0], ov[1], ov[2], ov[3]);
  if (ohi) {
    bf16x4 hv, lv;
#pragma unroll
    for (int j = 0; j < 4; ++j) {
      __bf16 hh = (__bf16)ov[j];
      hv[j] = hh;
      lv[j] = (__bf16)(ov[j] - (float)hh);
    }
    *(bf16x4*)(ohi + base) = hv;
    *(bf16x4*)(olo + base) = lv;
  }
}

// ---------------------------------------------------------------------------
// fp32 -> bf16 hi/lo split, float4 grid-stride.
__global__ __launch_bounds__(256) void split_kernel(const float* __restrict__ in,
                                                    __bf16* __restrict__ hi,
                                                    __bf16* __restrict__ lo,
                                                    int n4) {
  int idx = blockIdx.x * 256 + threadIdx.x;
  int stride = gridDim.x * 256;
  for (int i = idx; i < n4; i += stride) {
    float4 v = ((const float4*)in)[i];
    bf16x4 hv, lv;
#pragma unroll
    for (int j = 0; j < 4; ++j) {
      float f = (&v.x)[j];
      __bf16 hh = (__bf16)f;
      hv[j] = hh;
      lv[j] = (__bf16)(f - (float)hh);
    }
    ((bf16x4*)hi)[i] = hv;
    ((bf16x4*)lo)[i] = lv;
  }
}

// ---------------------------------------------------------------------------
// Split-bf16 MFMA GEMM (as round 2) + vt mode: when vt=1, Chi/Clo are written
// transposed per-head: Chi[((b*H+h)*64 + d)*S + i]  (M must be B_*S_, N=E_).
__global__ __launch_bounds__(256) void gemm_split(
    const __bf16* __restrict__ Ah, const __bf16* __restrict__ Al,
    const __bf16* __restrict__ Bh, const __bf16* __restrict__ Bl,
    const float* __restrict__ bias, const float* __restrict__ res,
    float* __restrict__ Cf, __bf16* __restrict__ Chi, __bf16* __restrict__ Clo,
    int M, int N, int K, float scale, int act, int vt) {
  __shared__ bf16x8 lds[2048];  // 32 KiB: Ah[0) Al[512) Bh[1024) Bl[1536)
  const int t = threadIdx.x;
  const int row0 = blockIdx.y * 128, col0 = blockIdx.x * 128;
  const int l = t & 63;
  const int w = t >> 6;
  const int wr = w >> 1, wc = w & 1;
  const int fr = l & 15, kg = l >> 4;
  const int wbase = t & 192;

  f32x4 acc[4][4];
#pragma unroll
  for (int i = 0; i < 4; ++i)
#pragma unroll
    for (int j = 0; j < 4; ++j) acc[i][j] = (f32x4){0.f, 0.f, 0.f, 0.f};

  for (int k0 = 0; k0 < K; k0 += 32) {
#pragma unroll
    for (int rnd = 0; rnd < 2; ++rnd) {
      int u = rnd * 256 + t;
      int rrow = u & 127, ukg = u >> 7;
      size_t goffA = (size_t)(row0 + rrow) * K + k0 + ukg * 8;
      size_t goffB = (size_t)(col0 + rrow) * K + k0 + ukg * 8;
      int lb = rnd * 256 + wbase;
      gl_lds16(Ah + goffA, &lds[lb]);
      gl_lds16(Al + goffA, &lds[512 + lb]);
      gl_lds16(Bh + goffB, &lds[1024 + lb]);
      gl_lds16(Bl + goffB, &lds[1536 + lb]);
    }
    __syncthreads();

    bf16x8 a_h[4], a_l[4], b_h[4], b_l[4];
#pragma unroll
    for (int i = 0; i < 4; ++i) {
      a_h[i] = lds[        kg * 128 + wr * 64 + i * 16 + fr];
      a_l[i] = lds[ 512  + kg * 128 + wr * 64 + i * 16 + fr];
      b_h[i] = lds[ 1024 + kg * 128 + wc * 64 + i * 16 + fr];
      b_l[i] = lds[ 1536 + kg * 128 + wc * 64 + i * 16 + fr];
    }
#pragma unroll
    for (int i = 0; i < 4; ++i)
#pragma unroll
      for (int j = 0; j < 4; ++j)
        acc[i][j] = __builtin_amdgcn_mfma_f32_16x16x32_bf16(a_h[i], b_h[j], acc[i][j], 0, 0, 0);
#pragma unroll
    for (int i = 0; i < 4; ++i)
#pragma unroll
      for (int j = 0; j < 4; ++j)
        acc[i][j] = __builtin_amdgcn_mfma_f32_16x16x32_bf16(a_h[i], b_l[j], acc[i][j], 0, 0, 0);
#pragma unroll
    for (int i = 0; i < 4; ++i)
#pragma unroll
      for (int j = 0; j < 4; ++j)
        acc[i][j] = __builtin_amdgcn_mfma_f32_16x16x32_bf16(a_l[i], b_h[j], acc[i][j], 0, 0, 0);
    __syncthreads();
  }

#pragma unroll
  for (int mi = 0; mi < 4; ++mi)
#pragma unroll
    for (int ni = 0; ni < 4; ++ni) {
      int col = col0 + wc * 64 + ni * 16 + fr;
      int rbase = row0 + wr * 64 + mi * 16 + kg * 4;
      float bsum = bias[col];
#pragma unroll
      for (int r = 0; r < 4; ++r) {
        float v = (acc[mi][ni][r] + bsum) * scale;
        if (act) {
          float zn = 0.7978845608028654f * (v + 0.044715f * v * v * v);
          float e = __expf(fminf(2.f * zn, 80.f));
          v = v * e / (e + 1.f);
        }
        size_t off = (size_t)(rbase + r) * N + col;
        if (res) v += res[off];
        if (Cf) Cf[off] = v;
        if (Chi) {
          __bf16 hh = (__bf16)v;
          __bf16 ll = (__bf16)(v - (float)hh);
          if (vt) {
            int tok = rbase + r;
            int bb2 = tok >> 11, ii = tok & 2047;
            int hh2 = col >> 6, dd = col & 63;
            size_t offt = ((((size_t)bb2 * H_ + hh2) * D_ + dd) << 11) + ii;
            Chi[offt] = hh; Clo[offt] = ll;
          } else {
            Chi[off] = hh; Clo[off] = ll;
          }
        }
      }
    }
}

// ---------------------------------------------------------------------------
// Sparse flash attention, split-bf16 MFMA.
// Block = (qt, h, b), 256 thr = 4 waves; wave w owns q-rows [qt*64+16w, +16).
// Tiles of 64 key-slots: far summary runs (packed, 8-col groups padded within
// each 33-col run) then near tiles jb in [qt-2, qt].
// K LDS: unit u = dg*64 + c  -> K[col c][d in 8dg..8dg+8)   (B-frag for QK^T)
// V LDS: unit u = jg*64 + d  -> V^T[d][j0(jg)..+8)          (B-frag for PV)
// Scores: Qh*Kh + Qh*Kl + Ql*Kh (fp32-accurate). PV: Ph*Vh + Ph*Vl.
__global__ __launch_bounds__(256) void attn_mfma(
    const __bf16* __restrict__ qhi, const __bf16* __restrict__ qlo,
    const __bf16* __restrict__ khi, const __bf16* __restrict__ klo,
    const __bf16* __restrict__ vth, const __bf16* __restrict__ vtl,
    __bf16* __restrict__ abhi, __bf16* __restrict__ ablo) {
  const int qt = blockIdx.x;
  const int h  = blockIdx.y;
  const int b  = blockIdx.z;
  const int t = threadIdx.x;
  const int l = t & 63;
  const int w = t >> 6;
  const int lanelo = l & 15, lanehi = l >> 4;

  __shared__ bf16x8 KhL[512], KlL[512], VhL[512], VlL[512];  // 8 KiB each
  __shared__ __align__(16) __bf16 Pl[4][16][72];             // per-wave P

  // Q A-frags: lane row = lanelo, k = 8*lanehi + 32*ks
  const int arow = qt * 64 + w * 16 + lanelo;
  size_t qoff = ((size_t)(b * S_ + arow)) * E_ + h * D_ + lanehi * 8;
  bf16x8 qh[2], ql[2];
  qh[0] = *(const bf16x8*)(qhi + qoff);      qh[1] = *(const bf16x8*)(qhi + qoff + 32);
  ql[0] = *(const bf16x8*)(qlo + qoff);      ql[1] = *(const bf16x8*)(qlo + qoff + 32);

  const int drow = qt * 64 + w * 16 + lanehi * 4;  // D-frag row base (+r)

  f32x4 o_acc[4];
#pragma unroll
  for (int n = 0; n < 4; ++n) o_acc[n] = (f32x4){0.f, 0.f, 0.f, 0.f};
  float mrow[4] = {-1e30f, -1e30f, -1e30f, -1e30f};
  float lrow[4] = {0.f, 0.f, 0.f, 0.f};

  const int nnear0 = (qt >= 2) ? (qt - 2) : 0;
  const int L = (qt - 2) * 64;
  int tmax = 0, nfar = 0;
  if (L > 96) {
    tmax = (L - 96 + 127) >> 7;
    nfar = (5 * tmax + 7) >> 3;
  }
  const int ntiles = nfar + (qt - nnear0 + 1);

  for (int tile = 0; tile < ntiles; ++tile) {
    const bool is_far = tile < nfar;
    const int jb = nnear0 + (tile - nfar);

    // ---- stage K / V^T (wave roles: 0=Kh 1=Kl 2=Vh 3=Vl)
    if (w < 2) {
      int c = l, jg; bool valid;
      if (is_far) {
        unsigned g8 = tile * 8 + (c >> 3);
        unsigned t5 = g8 / 5u, u = g8 - t5 * 5u;
        int oo = (int)(u * 8) + (c & 7);
        jg = 96 + ((int)t5 << 7) + oo;
        valid = (g8 < 5u * (unsigned)tmax) && (oo <= 32) && (jg < L);
      } else { jg = (jb << 6) + c; valid = true; }
      int tok = b * S_ + (valid ? jg : 0);
      const __bf16* src = (w == 0 ? khi : klo) + (size_t)tok * E_ + h * D_;
      bf16x8* dst = (w == 0 ? KhL : KlL);
#pragma unroll
      for (int dg = 0; dg < 8; ++dg) gl_lds16(src + dg * 8, dst + dg * 64);
    } else {
      const __bf16* src = (w == 2 ? vth : vtl) + ((size_t)((b * H_ + h) * D_ + l)) * S_;
      bf16x8* dst = (w == 2 ? VhL : VlL);
#pragma unroll
      for (int jgp = 0; jgp < 8; ++jgp) {
        int j0;
        if (is_far) {
          unsigned g8 = tile * 8 + jgp;
          unsigned t5 = g8 / 5u, u = g8 - t5 * 5u;
          j0 = (g8 < 5u * (unsigned)tmax) ? (96 + ((int)t5 << 7) + (int)u * 8) : 0;
        } else j0 = (jb << 6) + jgp * 8;
        gl_lds16(src + j0, dst + jgp * 64);
      }
    }
    __syncthreads();

    // ---- QK^T: 24 MFMA
    f32x4 s[4];
#pragma unroll
    for (int n = 0; n < 4; ++n) s[n] = (f32x4){0.f, 0.f, 0.f, 0.f};
#pragma unroll
    for (int ks = 0; ks < 2; ++ks) {
#pragma unroll
      for (int n = 0; n < 4; ++n) {
        bf16x8 kb_h = KhL[(4 * ks + lanehi) * 64 + n * 16 + lanelo];
        bf16x8 kb_l = KlL[(4 * ks + lanehi) * 64 + n * 16 + lanelo];
        s[n] = __builtin_amdgcn_mfma_f32_16x16x32_bf16(qh[ks], kb_h, s[n], 0, 0, 0);
        s[n] = __builtin_amdgcn_mfma_f32_16x16x32_bf16(qh[ks], kb_l, s[n], 0, 0, 0);
        s[n] = __builtin_amdgcn_mfma_f32_16x16x32_bf16(ql[ks], kb_h, s[n], 0, 0, 0);
      }
    }

    // ---- mask
    int jgc[4]; bool vldc[4], summc[4];
#pragma unroll
    for (int n = 0; n < 4; ++n) {
      int c = n * 16 + lanelo;
      if (is_far) {
        unsigned g8 = tile * 8 + (c >> 3);
        unsigned t5 = g8 / 5u, u = g8 - t5 * 5u;
        int oo = (int)(u * 8) + (c & 7);
        int jg = 96 + ((int)t5 << 7) + oo;
        jgc[n] = jg;
        vldc[n] = (g8 < 5u * (unsigned)tmax) && (oo <= 32) && (jg < L);
        summc[n] = true;
      } else {
        int jg = (jb << 6) + c;
        jgc[n] = jg; vldc[n] = true;
        int jm = jg & 127;
        summc[n] = (jg >= 96) && ((jm >= 96) || (jm == 0 && jg >= 128));
      }
    }
    float tm[4] = {-1e30f, -1e30f, -1e30f, -1e30f};
#pragma unroll
    for (int r = 0; r < 4; ++r) {
      int i = drow + r;
      int lb = (((i & 127) == 0) && i != 0) ? (i - 128) : ((i >> 7) << 7);
#pragma unroll
      for (int n = 0; n < 4; ++n) {
        bool ok = is_far ? vldc[n]
                         : ((jgc[n] <= i) && ((jgc[n] >= lb) || summc[n]));
        float sv = ok ? s[n][r] : -1e30f;
        s[n][r] = sv;
        tm[r] = fmaxf(tm[r], sv);
      }
    }
#pragma unroll
    for (int off = 1; off < 16; off <<= 1)
#pragma unroll
      for (int r = 0; r < 4; ++r) tm[r] = fmaxf(tm[r], __shfl_xor(tm[r], off));

    // ---- online softmax
    float psum[4] = {0.f, 0.f, 0.f, 0.f};
#pragma unroll
    for (int r = 0; r < 4; ++r) {
      float mnew = fmaxf(mrow[r], tm[r]);
      float alpha = __expf(mrow[r] - mnew);
      mrow[r] = mnew;
      lrow[r] *= alpha;
#pragma unroll
      for (int n = 0; n < 4; ++n) o_acc[n][r] *= alpha;
#pragma unroll
      for (int n = 0; n < 4; ++n) {
        float sv = s[n][r];
        float p = (sv > -1e29f) ? __expf(sv - mnew) : 0.f;
        s[n][r] = p;
        psum[r] += p;
      }
    }
#pragma unroll
    for (int off = 1; off < 16; off <<= 1)
#pragma unroll
      for (int r = 0; r < 4; ++r) psum[r] += __shfl_xor(psum[r], off);
#pragma unroll
    for (int r = 0; r < 4; ++r) lrow[r] += psum[r];

    // ---- P -> LDS (bf16), re-read as A-frags
#pragma unroll
    for (int r = 0; r < 4; ++r)
#pragma unroll
      for (int n = 0; n < 4; ++n)
        Pl[w][lanehi * 4 + r][n * 16 + lanelo] = (__bf16)s[n][r];
    bf16x8 pa[2];
    pa[0] = *(const bf16x8*)&Pl[w][lanelo][8 * lanehi];
    pa[1] = *(const bf16x8*)&Pl[w][lanelo][8 * lanehi + 32];

    // ---- PV: 16 MFMA
#pragma unroll
    for (int ks = 0; ks < 2; ++ks) {
#pragma unroll
      for (int n = 0; n < 4; ++n) {
        bf16x8 vb_h = VhL[(4 * ks + lanehi) * 64 + n * 16 + lanelo];
        bf16x8 vb_l = VlL[(4 * ks + lanehi) * 64 + n * 16 + lanelo];
        o_acc[n] = __builtin_amdgcn_mfma_f32_16x16x32_bf16(pa[ks], vb_h, o_acc[n], 0, 0, 0);
        o_acc[n] = __builtin_amdgcn_mfma_f32_16x16x32_bf16(pa[ks], vb_l, o_acc[n], 0, 0, 0);
      }
    }
    __syncthreads();
  }

  // ---- epilogue: O/l -> bf16 hi/lo
#pragma unroll
  for (int r = 0; r < 4; ++r) {
    float inv = 1.0f / lrow[r];
    int i = drow + r;
    size_t rb = ((size_t)(b * S_ + i)) * E_ + h * D_;
#pragma unroll
    for (int n = 0; n < 4; ++n) {
      float val = o_acc[n][r] * inv;
      __bf16 hh = (__bf16)val;
      abhi[rb + n * 16 + lanelo] = hh;
      ablo[rb + n * 16 + lanelo] = (__bf16)(val - (float)hh);
    }
  }
}

// ---------------------------------------------------------------------------
extern "C" void kernel_launch(void* const* d_in, const int* in_sizes, int n_in,
                              void* d_out, int out_size, void* d_ws, size_t ws_size,
                              hipStream_t stream) {
  const float* x      = (const float*)d_in[0];
  const float* ln1_g  = (const float*)d_in[1];
  const float* ln1_b  = (const float*)d_in[2];
  const float* ln2_g  = (const float*)d_in[3];
  const float* ln2_b  = (const float*)d_in[4];
  const float* wq     = (const float*)d_in[5];
  const float* bq     = (const float*)d_in[6];
  const float* wk     = (const float*)d_in[7];
  const float* bk     = (const float*)d_in[8];
  const float* wv     = (const float*)d_in[9];
  const float* bv     = (const float*)d_in[10];
  const float* wo     = (const float*)d_in[11];
  const float* bo     = (const float*)d_in[12];
  const float* w_fc   = (const float*)d_in[13];
  const float* b_fc   = (const float*)d_in[14];
  const float* w_proj = (const float*)d_in[15];
  const float* b_proj = (const float*)d_in[16];
  // d_in[17] = mask — computed in closed form in-kernel.

  char* W = (char*)d_ws;
  const size_t MB = (size_t)1 << 20;
  const int NTOK = B_ * S_;  // 8192

  // Workspace plan (MiB offsets, 224 total):
  // [0,32)    h fp32              -> l2o_hi [0,16) + l2o_lo [16,32) after WO
  // [32,64)   h_hi/h_lo           -> ab_hi/ab_lo after QKV -> wfc/wpj after WO
  // [64,96)   q_hi/q_lo           -> h2 fp32 after attn
  // [96,128)  k_hi/k_lo           -> fcb_hi (64 MiB, [96,160)) after attn
  // [128,160) vt_hi/vt_lo
  // [160,224) w-scratch (qkv/wo)  -> fcb_lo (64 MiB) after WO
  float*  h      = (float*)(W + 0 * MB);
  __bf16* h_hi   = (__bf16*)(W + 32 * MB);
  __bf16* h_lo   = (__bf16*)(W + 48 * MB);
  __bf16* q_hi   = (__bf16*)(W + 64 * MB);
  __bf16* q_lo   = (__bf16*)(W + 80 * MB);
  __bf16* k_hi   = (__bf16*)(W + 96 * MB);
  __bf16* k_lo   = (__bf16*)(W + 112 * MB);
  __bf16* vt_hi  = (__bf16*)(W + 128 * MB);
  __bf16* vt_lo  = (__bf16*)(W + 144 * MB);
  __bf16* ab_hi  = h_hi;
  __bf16* ab_lo  = h_lo;
  float*  h2     = (float*)(W + 64 * MB);
  __bf16* l2o_hi = (__bf16*)(W + 0 * MB);
  __bf16* l2o_lo = (__bf16*)(W + 16 * MB);
  __bf16* fcb_hi = (__bf16*)(W + 96 * MB);
  __bf16* fcb_lo = (__bf16*)(W + 160 * MB);
  __bf16* wq_hi  = (__bf16*)(W + 160 * MB);
  __bf16* wq_lo  = (__bf16*)(W + 162 * MB);
  __bf16* wk_hi  = (__bf16*)(W + 164 * MB);
  __bf16* wk_lo  = (__bf16*)(W + 166 * MB);
  __bf16* wv_hi  = (__bf16*)(W + 168 * MB);
  __bf16* wv_lo  = (__bf16*)(W + 170 * MB);
  __bf16* wo_hi  = (__bf16*)(W + 172 * MB);
  __bf16* wo_lo  = (__bf16*)(W + 174 * MB);
  __bf16* wfc_hi = (__bf16*)(W + 32 * MB);
  __bf16* wfc_lo = (__bf16*)(W + 40 * MB);
  __bf16* wpj_hi = (__bf16*)(W + 32 * MB);
  __bf16* wpj_lo = (__bf16*)(W + 40 * MB);
  float* out = (float*)d_out;

  const int SPLIT_BLKS = 2048;
  const int nw1 = E_ * E_ / 4;
  const int nw4 = 4 * E_ * E_ / 4;

  ln_kernel<<<NTOK, 256, 0, stream>>>(x, ln1_g, ln1_b, h, h_hi, h_lo);

  split_kernel<<<SPLIT_BLKS, 256, 0, stream>>>(wq, wq_hi, wq_lo, nw1);
  split_kernel<<<SPLIT_BLKS, 256, 0, stream>>>(wk, wk_hi, wk_lo, nw1);
  split_kernel<<<SPLIT_BLKS, 256, 0, stream>>>(wv, wv_hi, wv_lo, nw1);
  dim3 g1(E_ / 128, NTOK / 128);
  gemm_split<<<g1, 256, 0, stream>>>(h_hi, h_lo, wq_hi, wq_lo, bq, nullptr,
                                     nullptr, q_hi, q_lo, NTOK, E_, E_, 0.125f, 0, 0);
  gemm_split<<<g1, 256, 0, stream>>>(h_hi, h_lo, wk_hi, wk_lo, bk, nullptr,
                                     nullptr, k_hi, k_lo, NTOK, E_, E_, 1.0f, 0, 0);
  gemm_split<<<g1, 256, 0, stream>>>(h_hi, h_lo, wv_hi, wv_lo, bv, nullptr,
                                     nullptr, vt_hi, vt_lo, NTOK, E_, E_, 1.0f, 0, 1);

  attn_mfma<<<dim3(S_ / 64, H_, B_), 256, 0, stream>>>(q_hi, q_lo, k_hi, k_lo,
                                                       vt_hi, vt_lo, ab_hi, ab_lo);

  split_kernel<<<SPLIT_BLKS, 256, 0, stream>>>(wo, wo_hi, wo_lo, nw1);
  gemm_split<<<g1, 256, 0, stream>>>(ab_hi, ab_lo, wo_hi, wo_lo, bo, h,
                                     h2, nullptr, nullptr, NTOK, E_, E_, 1.0f, 0, 0);

  ln_kernel<<<NTOK, 256, 0, stream>>>(h2, ln2_g, ln2_b, nullptr, l2o_hi, l2o_lo);

  split_kernel<<<SPLIT_BLKS, 256, 0, stream>>>(w_fc, wfc_hi, wfc_lo, nw4);
  dim3 g2(4 * E_ / 128, NTOK / 128);
  gemm_split<<<g2, 256, 0, stream>>>(l2o_hi, l2o_lo, wfc_hi, wfc_lo, b_fc, nullptr,
                                     nullptr, fcb_hi, fcb_lo, NTOK, 4 * E_, E_, 1.0f, 1, 0);

  split_kernel<<<SPLIT_BLKS, 256, 0, stream>>>(w_proj, wpj_hi, wpj_lo, nw4);
  gemm_split<<<g1, 256, 0, stream>>>(fcb_hi, fcb_lo, wpj_hi, wpj_lo, b_proj, h2,
                                     out, nullptr, nullptr, NTOK, E_, 4 * E_, 1.0f, 0, 0);
}